// Round 1
// 537.443 us; speedup vs baseline: 1.0828x; 1.0828x over previous
//
#include <hip/hip_runtime.h>

// ---------------- CSR construction (R13, unchanged) ----------------

__global__ void count_kernel(const int* __restrict__ dst, int* __restrict__ counts, int E) {
    int e = blockIdx.x * 256 + threadIdx.x;
    if (e < E) atomicAdd(&counts[dst[e]], 1);
}

__global__ void scan_local(const int* __restrict__ counts, int* __restrict__ rowptr,
                           int* __restrict__ bsums, float* __restrict__ dinv, int N) {
    __shared__ int sm[256];
    int t = threadIdx.x;
    int gid = blockIdx.x * 256 + t;
    int v = (gid < N) ? counts[gid] : 0;
    if (gid < N) dinv[gid] = rsqrtf((float)v + 1.0f);
    int x = v;
    sm[t] = x; __syncthreads();
    for (int off = 1; off < 256; off <<= 1) {
        int y = (t >= off) ? sm[t - off] : 0;
        __syncthreads();
        x += y; sm[t] = x; __syncthreads();
    }
    if (gid < N) rowptr[gid] = x - v;
    if (t == 255) bsums[blockIdx.x] = x;
}

__global__ void scan_bsums(int* bsums, int nb) {
    __shared__ int sm[512];
    int t = threadIdx.x;
    int v = (t < nb) ? bsums[t] : 0;
    int x = v;
    sm[t] = x; __syncthreads();
    for (int off = 1; off < 512; off <<= 1) {
        int y = (t >= off) ? sm[t - off] : 0;
        __syncthreads();
        x += y; sm[t] = x; __syncthreads();
    }
    if (t < nb) bsums[t] = x - v;
}

__global__ void scan_add(int* __restrict__ rowptr, const int* __restrict__ bsums, int N) {
    int gid = blockIdx.x * 256 + threadIdx.x;
    if (gid < N) rowptr[gid] += bsums[blockIdx.x];
}

__global__ void fill_kernel(const int* __restrict__ src, const int* __restrict__ dst,
                            const int* __restrict__ rowptr, int* __restrict__ fillc,
                            const float* __restrict__ dinv,
                            int2* __restrict__ edges, int E) {
    int e = blockIdx.x * 256 + threadIdx.x;
    if (e < E) {
        int d = dst[e];
        int s = src[e];
        int pos = rowptr[d] + atomicAdd(&fillc[d], 1);
        edges[pos] = make_int2(s, __float_as_int(dinv[s]));
    }
}

// ---------------- xw = X @ W (R13 version, unchanged) ----------------

__global__ void __launch_bounds__(128)
gemm64_kernel(const float* __restrict__ X, const float* __restrict__ W,
              float* __restrict__ out, int N) {
    __shared__ float Wl[64 * 64];
    __shared__ float hbuf[2][256];
    int tid = threadIdx.x;
    int lane = tid & 63;
    for (int i = tid; i < 4096; i += 128) Wl[i] = W[i];
    __syncthreads();
    int wi = __builtin_amdgcn_readfirstlane(tid >> 6);
    float* hb = &hbuf[wi][0];
    int g0 = blockIdx.x * 2 + wi;
    int ng = gridDim.x * 2;
    int NG = (N + 3) >> 2;
    for (int g = g0; g < NG; g += ng) {
        int v0 = g * 4;
        float x0 = (v0 + 0 < N) ? X[(size_t)(v0 + 0) * 64 + lane] : 0.f;
        float x1 = (v0 + 1 < N) ? X[(size_t)(v0 + 1) * 64 + lane] : 0.f;
        float x2 = (v0 + 2 < N) ? X[(size_t)(v0 + 2) * 64 + lane] : 0.f;
        float x3 = (v0 + 3 < N) ? X[(size_t)(v0 + 3) * 64 + lane] : 0.f;
        *(float4*)&hb[lane * 4] = make_float4(x0, x1, x2, x3);
        float y0 = 0.f, y1 = 0.f, y2 = 0.f, y3 = 0.f;
#pragma unroll 8
        for (int k = 0; k < 64; ++k) {
            float4 hk = *(const float4*)&hb[k * 4];
            float w = Wl[k * 64 + lane];
            y0 = fmaf(hk.x, w, y0);
            y1 = fmaf(hk.y, w, y1);
            y2 = fmaf(hk.z, w, y2);
            y3 = fmaf(hk.w, w, y3);
        }
        if (v0 + 0 < N) out[(size_t)(v0 + 0) * 64 + lane] = y0;
        if (v0 + 1 < N) out[(size_t)(v0 + 1) * 64 + lane] = y1;
        if (v0 + 2 < N) out[(size_t)(v0 + 2) * 64 + lane] = y2;
        if (v0 + 3 < N) out[(size_t)(v0 + 3) * 64 + lane] = y3;
    }
}

// ------- layer1 agg + @W2: TWO nodes per wave, branch-free unroll-4 inner loop -------
// Key change vs R13: lanes >= nb hold (idx=0, ds=0), so the per-j guards are
// unnecessary — an unguarded pad iteration gathers XW[0] (broadcast, cache-hot)
// and fma's with 0. Branch-free body + manual unroll-4 => 8 independent gathers
// in flight per wave (vs 2), attacking the memory-latency bound.

__global__ void agg_mm_kernel(const float* __restrict__ XW, const int2* __restrict__ edges,
                              const int* __restrict__ rowptr, const int* __restrict__ counts,
                              const float* __restrict__ dinv, const float* __restrict__ bias,
                              const float* __restrict__ W2, float* __restrict__ Y, int N) {
    __shared__ float Wl[64 * 64];
    int tid = threadIdx.x;
    for (int i = tid; i < 4096; i += 256) Wl[i] = W2[i];
    __syncthreads();
    int lane = tid & 63, wave = tid >> 6;
    float bb = bias[lane];
    int NP = (N + 1) >> 1;
    int p0 = blockIdx.x * 4 + wave;
    int pstr = gridDim.x * 4;
    for (int p = p0; p < NP; p += pstr) {
        int vA = 2 * p, vB = 2 * p + 1;
        bool hasB = vB < N;
        int startA = __builtin_amdgcn_readfirstlane(rowptr[vA]);
        int cntA   = __builtin_amdgcn_readfirstlane(counts[vA]);
        int startB = hasB ? __builtin_amdgcn_readfirstlane(rowptr[vB]) : 0;
        int cntB   = hasB ? __builtin_amdgcn_readfirstlane(counts[vB]) : 0;
        float dvA = dinv[vA];
        float dvB = hasB ? dinv[vB] : 0.f;
        float accA = dvA * XW[(size_t)vA * 64 + lane];
        float accB = hasB ? dvB * XW[(size_t)vB * 64 + lane] : 0.f;
        int cntM = max(cntA, cntB);
        for (int base = 0; base < cntM; base += 64) {
            int nbA = min(64, cntA - base);
            int nbB = min(64, cntB - base);
            int idxA = 0, idxB = 0; float dsA = 0.f, dsB = 0.f;
            if (lane < nbA) { int2 e = edges[startA + base + lane]; idxA = e.x; dsA = __int_as_float(e.y); }
            if (lane < nbB) { int2 e = edges[startB + base + lane]; idxB = e.x; dsB = __int_as_float(e.y); }
            int nbM = max(nbA, nbB);
            int nb4 = (nbM + 3) & ~3;   // nbM <= 64, so j+3 <= 63: shfl lane always valid
            for (int j = 0; j < nb4; j += 4) {
                int   sA0 = __shfl(idxA, j + 0), sA1 = __shfl(idxA, j + 1);
                int   sA2 = __shfl(idxA, j + 2), sA3 = __shfl(idxA, j + 3);
                float dA0 = __shfl(dsA, j + 0),  dA1 = __shfl(dsA, j + 1);
                float dA2 = __shfl(dsA, j + 2),  dA3 = __shfl(dsA, j + 3);
                int   sB0 = __shfl(idxB, j + 0), sB1 = __shfl(idxB, j + 1);
                int   sB2 = __shfl(idxB, j + 2), sB3 = __shfl(idxB, j + 3);
                float dB0 = __shfl(dsB, j + 0),  dB1 = __shfl(dsB, j + 1);
                float dB2 = __shfl(dsB, j + 2),  dB3 = __shfl(dsB, j + 3);
                float xA0 = XW[(size_t)sA0 * 64 + lane];
                float xA1 = XW[(size_t)sA1 * 64 + lane];
                float xA2 = XW[(size_t)sA2 * 64 + lane];
                float xA3 = XW[(size_t)sA3 * 64 + lane];
                float xB0 = XW[(size_t)sB0 * 64 + lane];
                float xB1 = XW[(size_t)sB1 * 64 + lane];
                float xB2 = XW[(size_t)sB2 * 64 + lane];
                float xB3 = XW[(size_t)sB3 * 64 + lane];
                accA = fmaf(dA0, xA0, accA);
                accA = fmaf(dA1, xA1, accA);
                accA = fmaf(dA2, xA2, accA);
                accA = fmaf(dA3, xA3, accA);
                accB = fmaf(dB0, xB0, accB);
                accB = fmaf(dB1, xB1, accB);
                accB = fmaf(dB2, xB2, accB);
                accB = fmaf(dB3, xB3, accB);
            }
        }
        float hA = fmaxf(fmaf(dvA, accA, bb), 0.f);
        float hB = fmaxf(fmaf(dvB, accB, bb), 0.f);
        float yA = 0.f, yB = 0.f;
#pragma unroll 8
        for (int k = 0; k < 64; ++k) {
            float w = Wl[k * 64 + lane];
            yA = fmaf(__shfl(hA, k), w, yA);
            yB = fmaf(__shfl(hB, k), w, yB);
        }
        Y[(size_t)vA * 64 + lane] = yA;
        if (hasB) Y[(size_t)vB * 64 + lane] = yB;
    }
}

// ------- layer2 agg + MLP head: TWO nodes per wave, branch-free unroll-4 inner loop -------

__global__ void agg_head_kernel(const float* __restrict__ Yin, const int2* __restrict__ edges,
                                const int* __restrict__ rowptr, const int* __restrict__ counts,
                                const float* __restrict__ dinv, const float* __restrict__ b2,
                                const float* __restrict__ dW1, const float* __restrict__ db1,
                                const float* __restrict__ dW2, const float* __restrict__ db2,
                                float* __restrict__ out, int N) {
    __shared__ float D1[64 * 64];
    __shared__ float W2l[64 * 16];
    int tid = threadIdx.x;
    for (int i = tid; i < 4096; i += 256) D1[i] = dW1[i];
    for (int i = tid; i < 1024; i += 256) W2l[i] = dW2[i];
    __syncthreads();
    int lane = tid & 63, wave = tid >> 6;
    int c = lane & 15, part = lane >> 4;
    float bbl = b2[lane];
    float bb1 = db1[lane];
    float ob  = db2[c];
    int NP = (N + 1) >> 1;
    int p0 = blockIdx.x * 4 + wave;
    int pstr = gridDim.x * 4;
    for (int p = p0; p < NP; p += pstr) {
        int vA = 2 * p, vB = 2 * p + 1;
        bool hasB = vB < N;
        int startA = __builtin_amdgcn_readfirstlane(rowptr[vA]);
        int cntA   = __builtin_amdgcn_readfirstlane(counts[vA]);
        int startB = hasB ? __builtin_amdgcn_readfirstlane(rowptr[vB]) : 0;
        int cntB   = hasB ? __builtin_amdgcn_readfirstlane(counts[vB]) : 0;
        float dvA = dinv[vA];
        float dvB = hasB ? dinv[vB] : 0.f;
        float accA = dvA * Yin[(size_t)vA * 64 + lane];
        float accB = hasB ? dvB * Yin[(size_t)vB * 64 + lane] : 0.f;
        int cntM = max(cntA, cntB);
        for (int base = 0; base < cntM; base += 64) {
            int nbA = min(64, cntA - base);
            int nbB = min(64, cntB - base);
            int idxA = 0, idxB = 0; float dsA = 0.f, dsB = 0.f;
            if (lane < nbA) { int2 e = edges[startA + base + lane]; idxA = e.x; dsA = __int_as_float(e.y); }
            if (lane < nbB) { int2 e = edges[startB + base + lane]; idxB = e.x; dsB = __int_as_float(e.y); }
            int nbM = max(nbA, nbB);
            int nb4 = (nbM + 3) & ~3;
            for (int j = 0; j < nb4; j += 4) {
                int   sA0 = __shfl(idxA, j + 0), sA1 = __shfl(idxA, j + 1);
                int   sA2 = __shfl(idxA, j + 2), sA3 = __shfl(idxA, j + 3);
                float dA0 = __shfl(dsA, j + 0),  dA1 = __shfl(dsA, j + 1);
                float dA2 = __shfl(dsA, j + 2),  dA3 = __shfl(dsA, j + 3);
                int   sB0 = __shfl(idxB, j + 0), sB1 = __shfl(idxB, j + 1);
                int   sB2 = __shfl(idxB, j + 2), sB3 = __shfl(idxB, j + 3);
                float dB0 = __shfl(dsB, j + 0),  dB1 = __shfl(dsB, j + 1);
                float dB2 = __shfl(dsB, j + 2),  dB3 = __shfl(dsB, j + 3);
                float xA0 = Yin[(size_t)sA0 * 64 + lane];
                float xA1 = Yin[(size_t)sA1 * 64 + lane];
                float xA2 = Yin[(size_t)sA2 * 64 + lane];
                float xA3 = Yin[(size_t)sA3 * 64 + lane];
                float xB0 = Yin[(size_t)sB0 * 64 + lane];
                float xB1 = Yin[(size_t)sB1 * 64 + lane];
                float xB2 = Yin[(size_t)sB2 * 64 + lane];
                float xB3 = Yin[(size_t)sB3 * 64 + lane];
                accA = fmaf(dA0, xA0, accA);
                accA = fmaf(dA1, xA1, accA);
                accA = fmaf(dA2, xA2, accA);
                accA = fmaf(dA3, xA3, accA);
                accB = fmaf(dB0, xB0, accB);
                accB = fmaf(dB1, xB1, accB);
                accB = fmaf(dB2, xB2, accB);
                accB = fmaf(dB3, xB3, accB);
            }
        }
        float hA = fmaxf(fmaf(dvA, accA, bbl), 0.f);
        float hB = fmaxf(fmaf(dvB, accB, bbl), 0.f);
        float aA = bb1, aB = bb1;
#pragma unroll 8
        for (int k = 0; k < 64; ++k) {
            float w = D1[k * 64 + lane];
            aA = fmaf(__shfl(hA, k), w, aA);
            aB = fmaf(__shfl(hB, k), w, aB);
        }
        aA = fmaxf(aA, 0.f); aB = fmaxf(aB, 0.f);
        float oA = 0.f, oB = 0.f;
#pragma unroll 8
        for (int kk = 0; kk < 16; ++kk) {
            float w = W2l[(part * 16 + kk) * 16 + c];
            oA = fmaf(__shfl(aA, part * 16 + kk), w, oA);
            oB = fmaf(__shfl(aB, part * 16 + kk), w, oB);
        }
        oA += __shfl_xor(oA, 16); oA += __shfl_xor(oA, 32);
        oB += __shfl_xor(oB, 16); oB += __shfl_xor(oB, 32);
        if (lane < 16) {
            out[(size_t)vA * 16 + lane] = oA + ob;
            if (hasB) out[(size_t)vB * 16 + lane] = oB + ob;
        }
    }
}

// ---------------- launch ----------------

extern "C" void kernel_launch(void* const* d_in, const int* in_sizes, int n_in,
                              void* d_out, int out_size, void* d_ws, size_t ws_size,
                              hipStream_t stream) {
    const float* x   = (const float*)d_in[0];
    const int*   ei  = (const int*)d_in[1];
    const float* W1  = (const float*)d_in[2];
    const float* b1  = (const float*)d_in[3];
    const float* W2  = (const float*)d_in[4];
    const float* b2  = (const float*)d_in[5];
    const float* dW1 = (const float*)d_in[6];
    const float* db1 = (const float*)d_in[7];
    const float* dW2 = (const float*)d_in[8];
    const float* db2 = (const float*)d_in[9];
    float* out = (float*)d_out;

    int N = in_sizes[0] / 64;
    int E = in_sizes[1] / 2;
    const int* src = ei;
    const int* dst = ei + E;

    size_t off = 0;
    auto alloc = [&](size_t bytes) {
        void* p = (char*)d_ws + off;
        off += (bytes + 511) & ~(size_t)511;
        return p;
    };
    int Npad = (N + 127) & ~127;
    int*   counts = (int*)alloc((size_t)Npad * 8);     // [counts | fillc]
    int*   fillc  = counts + Npad;
    int*   rowptr = (int*)alloc((size_t)N * 4);
    int*   bsums  = (int*)alloc(512 * 4);
    int2*  edges  = (int2*)alloc((size_t)E * 8);
    float* dinv   = (float*)alloc((size_t)N * 4);
    float* xw     = (float*)alloc((size_t)N * 64 * 4);
    float* yw     = (float*)alloc((size_t)N * 64 * 4);

    hipMemsetAsync(counts, 0, (size_t)Npad * 8, stream);

    int nbN = (N + 255) / 256;
    int nbE = (E + 255) / 256;

    count_kernel<<<nbE, 256, 0, stream>>>(dst, counts, E);
    scan_local<<<nbN, 256, 0, stream>>>(counts, rowptr, bsums, dinv, N);
    scan_bsums<<<1, 512, 0, stream>>>(bsums, nbN);
    scan_add<<<nbN, 256, 0, stream>>>(rowptr, bsums, N);
    fill_kernel<<<nbE, 256, 0, stream>>>(src, dst, rowptr, fillc, dinv, edges, E);

    gemm64_kernel<<<4096, 128, 0, stream>>>(x, W1, xw, N);
    agg_mm_kernel<<<2048, 256, 0, stream>>>(xw, edges, rowptr, counts, dinv, b1, W2, yw, N);
    agg_head_kernel<<<2048, 256, 0, stream>>>(yw, edges, rowptr, counts, dinv, b2,
                                              dW1, db1, dW2, db2, out, N);
}

// Round 2
// 535.963 us; speedup vs baseline: 1.0858x; 1.0028x over previous
//
#include <hip/hip_runtime.h>

// ---------------- CSR construction (unchanged) ----------------

__global__ void count_kernel(const int* __restrict__ dst, int* __restrict__ counts, int E) {
    int e = blockIdx.x * 256 + threadIdx.x;
    if (e < E) atomicAdd(&counts[dst[e]], 1);
}

__global__ void scan_local(const int* __restrict__ counts, int* __restrict__ rowptr,
                           int* __restrict__ bsums, float* __restrict__ dinv, int N) {
    __shared__ int sm[256];
    int t = threadIdx.x;
    int gid = blockIdx.x * 256 + t;
    int v = (gid < N) ? counts[gid] : 0;
    if (gid < N) dinv[gid] = rsqrtf((float)v + 1.0f);
    int x = v;
    sm[t] = x; __syncthreads();
    for (int off = 1; off < 256; off <<= 1) {
        int y = (t >= off) ? sm[t - off] : 0;
        __syncthreads();
        x += y; sm[t] = x; __syncthreads();
    }
    if (gid < N) rowptr[gid] = x - v;
    if (t == 255) bsums[blockIdx.x] = x;
}

__global__ void scan_bsums(int* bsums, int nb) {
    __shared__ int sm[512];
    int t = threadIdx.x;
    int v = (t < nb) ? bsums[t] : 0;
    int x = v;
    sm[t] = x; __syncthreads();
    for (int off = 1; off < 512; off <<= 1) {
        int y = (t >= off) ? sm[t - off] : 0;
        __syncthreads();
        x += y; sm[t] = x; __syncthreads();
    }
    if (t < nb) bsums[t] = x - v;
}

__global__ void scan_add(int* __restrict__ rowptr, const int* __restrict__ bsums, int N) {
    int gid = blockIdx.x * 256 + threadIdx.x;
    if (gid < N) rowptr[gid] += bsums[blockIdx.x];
}

__global__ void fill_kernel(const int* __restrict__ src, const int* __restrict__ dst,
                            const int* __restrict__ rowptr, int* __restrict__ fillc,
                            const float* __restrict__ dinv,
                            int2* __restrict__ edges, int E) {
    int e = blockIdx.x * 256 + threadIdx.x;
    if (e < E) {
        int d = dst[e];
        int s = src[e];
        int pos = rowptr[d] + atomicAdd(&fillc[d], 1);
        edges[pos] = make_int2(s, __float_as_int(dinv[s]));
    }
}

// ---------------- xw = X @ W (unchanged) ----------------

__global__ void __launch_bounds__(128)
gemm64_kernel(const float* __restrict__ X, const float* __restrict__ W,
              float* __restrict__ out, int N) {
    __shared__ float Wl[64 * 64];
    __shared__ float hbuf[2][256];
    int tid = threadIdx.x;
    int lane = tid & 63;
    for (int i = tid; i < 4096; i += 128) Wl[i] = W[i];
    __syncthreads();
    int wi = __builtin_amdgcn_readfirstlane(tid >> 6);
    float* hb = &hbuf[wi][0];
    int g0 = blockIdx.x * 2 + wi;
    int ng = gridDim.x * 2;
    int NG = (N + 3) >> 2;
    for (int g = g0; g < NG; g += ng) {
        int v0 = g * 4;
        float x0 = (v0 + 0 < N) ? X[(size_t)(v0 + 0) * 64 + lane] : 0.f;
        float x1 = (v0 + 1 < N) ? X[(size_t)(v0 + 1) * 64 + lane] : 0.f;
        float x2 = (v0 + 2 < N) ? X[(size_t)(v0 + 2) * 64 + lane] : 0.f;
        float x3 = (v0 + 3 < N) ? X[(size_t)(v0 + 3) * 64 + lane] : 0.f;
        *(float4*)&hb[lane * 4] = make_float4(x0, x1, x2, x3);
        float y0 = 0.f, y1 = 0.f, y2 = 0.f, y3 = 0.f;
#pragma unroll 8
        for (int k = 0; k < 64; ++k) {
            float4 hk = *(const float4*)&hb[k * 4];
            float w = Wl[k * 64 + lane];
            y0 = fmaf(hk.x, w, y0);
            y1 = fmaf(hk.y, w, y1);
            y2 = fmaf(hk.z, w, y2);
            y3 = fmaf(hk.w, w, y3);
        }
        if (v0 + 0 < N) out[(size_t)(v0 + 0) * 64 + lane] = y0;
        if (v0 + 1 < N) out[(size_t)(v0 + 1) * 64 + lane] = y1;
        if (v0 + 2 < N) out[(size_t)(v0 + 2) * 64 + lane] = y2;
        if (v0 + 3 < N) out[(size_t)(v0 + 3) * 64 + lane] = y3;
    }
}

// ------- layer1 agg + @W2: float4-gather, 4 edge-groups per wave -------
// Wave splits into 4 groups of 16 lanes; lane holds features c..c+3 (c=(lane&15)*4).
// One global_load_dwordx4 fetches 4 node rows (1 KB) => 4 edges per load instr,
// 16 edges in flight per wait window (2 chains x unroll 2). Cross-group partial
// sums merged with shfl_xor(16/32). Pad lanes hold (idx=0, ds=0) -> harmless
// hot-line gather of row 0 times 0.0.

__global__ void agg_mm_kernel(const float* __restrict__ XW, const int2* __restrict__ edges,
                              const int* __restrict__ rowptr, const int* __restrict__ counts,
                              const float* __restrict__ dinv, const float* __restrict__ bias,
                              const float* __restrict__ W2, float* __restrict__ Y, int N) {
    __shared__ float Wl[64 * 64];
    __shared__ float hb[4][2][64];
    int tid = threadIdx.x;
    for (int i = tid; i < 4096; i += 256) Wl[i] = W2[i];
    __syncthreads();
    int lane = tid & 63, wave = tid >> 6;
    int g = lane >> 4;
    int cb = (lane & 15) * 4;
    float4 bb4 = *(const float4*)&bias[cb];
    int NP = (N + 1) >> 1;
    int p0 = blockIdx.x * 4 + wave;
    int pstr = gridDim.x * 4;
    for (int p = p0; p < NP; p += pstr) {
        int vA = 2 * p, vB = 2 * p + 1;
        bool hasB = vB < N;
        int startA = __builtin_amdgcn_readfirstlane(rowptr[vA]);
        int cntA   = __builtin_amdgcn_readfirstlane(counts[vA]);
        int startB = hasB ? __builtin_amdgcn_readfirstlane(rowptr[vB]) : 0;
        int cntB   = hasB ? __builtin_amdgcn_readfirstlane(counts[vB]) : 0;
        float dvA = dinv[vA];
        float dvB = hasB ? dinv[vB] : 0.f;
        float4 aA = make_float4(0.f, 0.f, 0.f, 0.f);
        float4 aB = make_float4(0.f, 0.f, 0.f, 0.f);
        int cntM = max(cntA, cntB);
        for (int base = 0; base < cntM; base += 64) {
            int nbA = min(64, cntA - base);
            int nbB = min(64, cntB - base);
            int idxA = 0, idxB = 0; float dsA = 0.f, dsB = 0.f;
            if (lane < nbA) { int2 e = edges[startA + base + lane]; idxA = e.x; dsA = __int_as_float(e.y); }
            if (lane < nbB) { int2 e = edges[startB + base + lane]; idxB = e.x; dsB = __int_as_float(e.y); }
            int nbM = max(nbA, nbB);
            int nt = (nbM + 3) >> 2;
            nt = (nt + 1) & ~1;           // even => unroll-2; nt<=16 so shfl idx <= 63
            for (int t = 0; t < nt; t += 2) {
                int l0 = 4 * t + g;
                int l1 = l0 + 4;
                int   sA0 = __shfl(idxA, l0); float fA0 = __shfl(dsA, l0);
                int   sA1 = __shfl(idxA, l1); float fA1 = __shfl(dsA, l1);
                int   sB0 = __shfl(idxB, l0); float fB0 = __shfl(dsB, l0);
                int   sB1 = __shfl(idxB, l1); float fB1 = __shfl(dsB, l1);
                float4 xA0 = *(const float4*)&XW[(size_t)sA0 * 64 + cb];
                float4 xA1 = *(const float4*)&XW[(size_t)sA1 * 64 + cb];
                float4 xB0 = *(const float4*)&XW[(size_t)sB0 * 64 + cb];
                float4 xB1 = *(const float4*)&XW[(size_t)sB1 * 64 + cb];
                aA.x = fmaf(fA0, xA0.x, aA.x); aA.y = fmaf(fA0, xA0.y, aA.y);
                aA.z = fmaf(fA0, xA0.z, aA.z); aA.w = fmaf(fA0, xA0.w, aA.w);
                aA.x = fmaf(fA1, xA1.x, aA.x); aA.y = fmaf(fA1, xA1.y, aA.y);
                aA.z = fmaf(fA1, xA1.z, aA.z); aA.w = fmaf(fA1, xA1.w, aA.w);
                aB.x = fmaf(fB0, xB0.x, aB.x); aB.y = fmaf(fB0, xB0.y, aB.y);
                aB.z = fmaf(fB0, xB0.z, aB.z); aB.w = fmaf(fB0, xB0.w, aB.w);
                aB.x = fmaf(fB1, xB1.x, aB.x); aB.y = fmaf(fB1, xB1.y, aB.y);
                aB.z = fmaf(fB1, xB1.z, aB.z); aB.w = fmaf(fB1, xB1.w, aB.w);
            }
        }
        // cross-group reduce (4 partial sums -> total, all lanes end with the sum)
        aA.x += __shfl_xor(aA.x, 16); aA.x += __shfl_xor(aA.x, 32);
        aA.y += __shfl_xor(aA.y, 16); aA.y += __shfl_xor(aA.y, 32);
        aA.z += __shfl_xor(aA.z, 16); aA.z += __shfl_xor(aA.z, 32);
        aA.w += __shfl_xor(aA.w, 16); aA.w += __shfl_xor(aA.w, 32);
        aB.x += __shfl_xor(aB.x, 16); aB.x += __shfl_xor(aB.x, 32);
        aB.y += __shfl_xor(aB.y, 16); aB.y += __shfl_xor(aB.y, 32);
        aB.z += __shfl_xor(aB.z, 16); aB.z += __shfl_xor(aB.z, 32);
        aB.w += __shfl_xor(aB.w, 16); aB.w += __shfl_xor(aB.w, 32);
        // self-loop + bias + relu in float4 layout
        float4 xsA = *(const float4*)&XW[(size_t)vA * 64 + cb];
        int vBs = hasB ? vB : vA;
        float4 xsB = *(const float4*)&XW[(size_t)vBs * 64 + cb];
        float4 h4A, h4B;
        h4A.x = fmaxf(fmaf(dvA, fmaf(dvA, xsA.x, aA.x), bb4.x), 0.f);
        h4A.y = fmaxf(fmaf(dvA, fmaf(dvA, xsA.y, aA.y), bb4.y), 0.f);
        h4A.z = fmaxf(fmaf(dvA, fmaf(dvA, xsA.z, aA.z), bb4.z), 0.f);
        h4A.w = fmaxf(fmaf(dvA, fmaf(dvA, xsA.w, aA.w), bb4.w), 0.f);
        h4B.x = fmaxf(fmaf(dvB, fmaf(dvB, xsB.x, aB.x), bb4.x), 0.f);
        h4B.y = fmaxf(fmaf(dvB, fmaf(dvB, xsB.y, aB.y), bb4.y), 0.f);
        h4B.z = fmaxf(fmaf(dvB, fmaf(dvB, xsB.z, aB.z), bb4.z), 0.f);
        h4B.w = fmaxf(fmaf(dvB, fmaf(dvB, xsB.w, aB.w), bb4.w), 0.f);
        // layout convert float4@16lanes -> feature=lane via per-wave LDS (in-wave, no barrier;
        // same pattern as gemm64's hbuf)
        if (g == 0) {
            *(float4*)&hb[wave][0][cb] = h4A;
            *(float4*)&hb[wave][1][cb] = h4B;
        }
        float hA = hb[wave][0][lane];
        float hB = hb[wave][1][lane];
        float yA = 0.f, yB = 0.f;
#pragma unroll 8
        for (int k = 0; k < 64; ++k) {
            float w = Wl[k * 64 + lane];
            yA = fmaf(__shfl(hA, k), w, yA);
            yB = fmaf(__shfl(hB, k), w, yB);
        }
        Y[(size_t)vA * 64 + lane] = yA;
        if (hasB) Y[(size_t)vB * 64 + lane] = yB;
    }
}

// ------- layer2 agg + MLP head: same float4-gather structure -------

__global__ void agg_head_kernel(const float* __restrict__ Yin, const int2* __restrict__ edges,
                                const int* __restrict__ rowptr, const int* __restrict__ counts,
                                const float* __restrict__ dinv, const float* __restrict__ b2,
                                const float* __restrict__ dW1, const float* __restrict__ db1,
                                const float* __restrict__ dW2, const float* __restrict__ db2,
                                float* __restrict__ out, int N) {
    __shared__ float D1[64 * 64];
    __shared__ float W2l[64 * 16];
    __shared__ float hb[4][2][64];
    int tid = threadIdx.x;
    for (int i = tid; i < 4096; i += 256) D1[i] = dW1[i];
    for (int i = tid; i < 1024; i += 256) W2l[i] = dW2[i];
    __syncthreads();
    int lane = tid & 63, wave = tid >> 6;
    int g = lane >> 4;
    int cb = (lane & 15) * 4;
    int c = lane & 15, part = lane >> 4;
    float4 bb4 = *(const float4*)&b2[cb];
    float bb1 = db1[lane];
    float ob  = db2[c];
    int NP = (N + 1) >> 1;
    int p0 = blockIdx.x * 4 + wave;
    int pstr = gridDim.x * 4;
    for (int p = p0; p < NP; p += pstr) {
        int vA = 2 * p, vB = 2 * p + 1;
        bool hasB = vB < N;
        int startA = __builtin_amdgcn_readfirstlane(rowptr[vA]);
        int cntA   = __builtin_amdgcn_readfirstlane(counts[vA]);
        int startB = hasB ? __builtin_amdgcn_readfirstlane(rowptr[vB]) : 0;
        int cntB   = hasB ? __builtin_amdgcn_readfirstlane(counts[vB]) : 0;
        float dvA = dinv[vA];
        float dvB = hasB ? dinv[vB] : 0.f;
        float4 aA = make_float4(0.f, 0.f, 0.f, 0.f);
        float4 aB = make_float4(0.f, 0.f, 0.f, 0.f);
        int cntM = max(cntA, cntB);
        for (int base = 0; base < cntM; base += 64) {
            int nbA = min(64, cntA - base);
            int nbB = min(64, cntB - base);
            int idxA = 0, idxB = 0; float dsA = 0.f, dsB = 0.f;
            if (lane < nbA) { int2 e = edges[startA + base + lane]; idxA = e.x; dsA = __int_as_float(e.y); }
            if (lane < nbB) { int2 e = edges[startB + base + lane]; idxB = e.x; dsB = __int_as_float(e.y); }
            int nbM = max(nbA, nbB);
            int nt = (nbM + 3) >> 2;
            nt = (nt + 1) & ~1;
            for (int t = 0; t < nt; t += 2) {
                int l0 = 4 * t + g;
                int l1 = l0 + 4;
                int   sA0 = __shfl(idxA, l0); float fA0 = __shfl(dsA, l0);
                int   sA1 = __shfl(idxA, l1); float fA1 = __shfl(dsA, l1);
                int   sB0 = __shfl(idxB, l0); float fB0 = __shfl(dsB, l0);
                int   sB1 = __shfl(idxB, l1); float fB1 = __shfl(dsB, l1);
                float4 xA0 = *(const float4*)&Yin[(size_t)sA0 * 64 + cb];
                float4 xA1 = *(const float4*)&Yin[(size_t)sA1 * 64 + cb];
                float4 xB0 = *(const float4*)&Yin[(size_t)sB0 * 64 + cb];
                float4 xB1 = *(const float4*)&Yin[(size_t)sB1 * 64 + cb];
                aA.x = fmaf(fA0, xA0.x, aA.x); aA.y = fmaf(fA0, xA0.y, aA.y);
                aA.z = fmaf(fA0, xA0.z, aA.z); aA.w = fmaf(fA0, xA0.w, aA.w);
                aA.x = fmaf(fA1, xA1.x, aA.x); aA.y = fmaf(fA1, xA1.y, aA.y);
                aA.z = fmaf(fA1, xA1.z, aA.z); aA.w = fmaf(fA1, xA1.w, aA.w);
                aB.x = fmaf(fB0, xB0.x, aB.x); aB.y = fmaf(fB0, xB0.y, aB.y);
                aB.z = fmaf(fB0, xB0.z, aB.z); aB.w = fmaf(fB0, xB0.w, aB.w);
                aB.x = fmaf(fB1, xB1.x, aB.x); aB.y = fmaf(fB1, xB1.y, aB.y);
                aB.z = fmaf(fB1, xB1.z, aB.z); aB.w = fmaf(fB1, xB1.w, aB.w);
            }
        }
        aA.x += __shfl_xor(aA.x, 16); aA.x += __shfl_xor(aA.x, 32);
        aA.y += __shfl_xor(aA.y, 16); aA.y += __shfl_xor(aA.y, 32);
        aA.z += __shfl_xor(aA.z, 16); aA.z += __shfl_xor(aA.z, 32);
        aA.w += __shfl_xor(aA.w, 16); aA.w += __shfl_xor(aA.w, 32);
        aB.x += __shfl_xor(aB.x, 16); aB.x += __shfl_xor(aB.x, 32);
        aB.y += __shfl_xor(aB.y, 16); aB.y += __shfl_xor(aB.y, 32);
        aB.z += __shfl_xor(aB.z, 16); aB.z += __shfl_xor(aB.z, 32);
        aB.w += __shfl_xor(aB.w, 16); aB.w += __shfl_xor(aB.w, 32);
        float4 xsA = *(const float4*)&Yin[(size_t)vA * 64 + cb];
        int vBs = hasB ? vB : vA;
        float4 xsB = *(const float4*)&Yin[(size_t)vBs * 64 + cb];
        float4 h4A, h4B;
        h4A.x = fmaxf(fmaf(dvA, fmaf(dvA, xsA.x, aA.x), bb4.x), 0.f);
        h4A.y = fmaxf(fmaf(dvA, fmaf(dvA, xsA.y, aA.y), bb4.y), 0.f);
        h4A.z = fmaxf(fmaf(dvA, fmaf(dvA, xsA.z, aA.z), bb4.z), 0.f);
        h4A.w = fmaxf(fmaf(dvA, fmaf(dvA, xsA.w, aA.w), bb4.w), 0.f);
        h4B.x = fmaxf(fmaf(dvB, fmaf(dvB, xsB.x, aB.x), bb4.x), 0.f);
        h4B.y = fmaxf(fmaf(dvB, fmaf(dvB, xsB.y, aB.y), bb4.y), 0.f);
        h4B.z = fmaxf(fmaf(dvB, fmaf(dvB, xsB.z, aB.z), bb4.z), 0.f);
        h4B.w = fmaxf(fmaf(dvB, fmaf(dvB, xsB.w, aB.w), bb4.w), 0.f);
        if (g == 0) {
            *(float4*)&hb[wave][0][cb] = h4A;
            *(float4*)&hb[wave][1][cb] = h4B;
        }
        float hA = hb[wave][0][lane];
        float hB = hb[wave][1][lane];
        float aAv = bb1, aBv = bb1;
#pragma unroll 8
        for (int k = 0; k < 64; ++k) {
            float w = D1[k * 64 + lane];
            aAv = fmaf(__shfl(hA, k), w, aAv);
            aBv = fmaf(__shfl(hB, k), w, aBv);
        }
        aAv = fmaxf(aAv, 0.f); aBv = fmaxf(aBv, 0.f);
        float oA = 0.f, oB = 0.f;
#pragma unroll 8
        for (int kk = 0; kk < 16; ++kk) {
            float w = W2l[(part * 16 + kk) * 16 + c];
            oA = fmaf(__shfl(aAv, part * 16 + kk), w, oA);
            oB = fmaf(__shfl(aBv, part * 16 + kk), w, oB);
        }
        oA += __shfl_xor(oA, 16); oA += __shfl_xor(oA, 32);
        oB += __shfl_xor(oB, 16); oB += __shfl_xor(oB, 32);
        if (lane < 16) {
            out[(size_t)vA * 16 + lane] = oA + ob;
            if (hasB) out[(size_t)vB * 16 + lane] = oB + ob;
        }
    }
}

// ---------------- launch ----------------

extern "C" void kernel_launch(void* const* d_in, const int* in_sizes, int n_in,
                              void* d_out, int out_size, void* d_ws, size_t ws_size,
                              hipStream_t stream) {
    const float* x   = (const float*)d_in[0];
    const int*   ei  = (const int*)d_in[1];
    const float* W1  = (const float*)d_in[2];
    const float* b1  = (const float*)d_in[3];
    const float* W2  = (const float*)d_in[4];
    const float* b2  = (const float*)d_in[5];
    const float* dW1 = (const float*)d_in[6];
    const float* db1 = (const float*)d_in[7];
    const float* dW2 = (const float*)d_in[8];
    const float* db2 = (const float*)d_in[9];
    float* out = (float*)d_out;

    int N = in_sizes[0] / 64;
    int E = in_sizes[1] / 2;
    const int* src = ei;
    const int* dst = ei + E;

    size_t off = 0;
    auto alloc = [&](size_t bytes) {
        void* p = (char*)d_ws + off;
        off += (bytes + 511) & ~(size_t)511;
        return p;
    };
    int Npad = (N + 127) & ~127;
    int*   counts = (int*)alloc((size_t)Npad * 8);     // [counts | fillc]
    int*   fillc  = counts + Npad;
    int*   rowptr = (int*)alloc((size_t)N * 4);
    int*   bsums  = (int*)alloc(512 * 4);
    int2*  edges  = (int2*)alloc((size_t)E * 8);
    float* dinv   = (float*)alloc((size_t)N * 4);
    float* xw     = (float*)alloc((size_t)N * 64 * 4);
    float* yw     = (float*)alloc((size_t)N * 64 * 4);

    hipMemsetAsync(counts, 0, (size_t)Npad * 8, stream);

    int nbN = (N + 255) / 256;
    int nbE = (E + 255) / 256;

    count_kernel<<<nbE, 256, 0, stream>>>(dst, counts, E);
    scan_local<<<nbN, 256, 0, stream>>>(counts, rowptr, bsums, dinv, N);
    scan_bsums<<<1, 512, 0, stream>>>(bsums, nbN);
    scan_add<<<nbN, 256, 0, stream>>>(rowptr, bsums, N);
    fill_kernel<<<nbE, 256, 0, stream>>>(src, dst, rowptr, fillc, dinv, edges, E);

    gemm64_kernel<<<4096, 128, 0, stream>>>(x, W1, xw, N);
    agg_mm_kernel<<<2048, 256, 0, stream>>>(xw, edges, rowptr, counts, dinv, b1, W2, yw, N);
    agg_head_kernel<<<2048, 256, 0, stream>>>(yw, edges, rowptr, counts, dinv, b2,
                                              dW1, db1, dW2, db2, out, N);
}